// Round 12
// baseline (744.160 us; speedup 1.0000x reference)
//
#include <hip/hip_runtime.h>
#include <math.h>

#define CCH 256
#define HWP 65536
#define PCI 40   // padded ci stride (shorts) in LDS

typedef short short8 __attribute__((ext_vector_type(8)));
typedef float f32x4 __attribute__((ext_vector_type(4)));
typedef unsigned short us4 __attribute__((ext_vector_type(4)));

__device__ inline unsigned short f2bf(float f) {
  unsigned u = __float_as_uint(f);
  return (unsigned short)((u + 0x7FFFu + ((u >> 16) & 1u)) >> 16);
}
__device__ inline float bf2f(unsigned short s) {
  return __uint_as_float(((unsigned)s) << 16);
}

__device__ inline void mfma_bf16(f32x4& d, short8 a, short8 b) {
  asm volatile("v_mfma_f32_16x16x32_bf16 %0, %1, %2, %0" : "+v"(d) : "v"(a), "v"(b));
}

// ---- ws layout (bytes) ----
static const size_t BUF_B_OFF = 67108864;        // bufA @0 (64MB), bufB @64MB
static const size_t TAIL_OFF  = 134217728;
static const size_t KEYS_OFF  = TAIL_OFF;
static const size_t HIST_OFF  = TAIL_OFF + 262144;
static const size_t STATE_OFF = TAIL_OFF + 263168;
static const size_t IDX_OFF   = TAIL_OFF + 263424;
static const size_t EQ_OFF    = TAIL_OFF + 271616;
static const size_t OA_OFF    = 6291456;
static const size_t WTI_OFF   = 8388608;
static const size_t WTO_OFF   = 9437184;
static const size_t SROWS_OFF = 10485760;
static const size_t WT5_OFF   = 20971520;        // bf16 wB[256][2304] 1.18MB
static const size_t QB_OFF    = 31457280;
static const size_t KB_OFF    = 32505856;
static const size_t VT_OFF    = 33554432;
static const size_t CPK_OFF   = 37748736;
static const size_t DPK_OFF   = 44040192;

struct SelState { unsigned int P; int kneed; int nGreater; int nEqual; };

__global__ void k_init(unsigned int* hist, SelState* st) {
  int t = threadIdx.x;
  hist[t] = 0;
  if (t == 0) { st->P = 0u; st->kneed = 2048; st->nGreater = 0; st->nEqual = 0; }
}

// 1x1 conv 768->256 on 8x8
__global__ void k_wtconv(const float* __restrict__ swint, const float* __restrict__ w,
                         const float* __restrict__ b, float* __restrict__ out) {
  int co = blockIdx.x, p = threadIdx.x;
  float acc = b[co];
  for (int ci = 0; ci < 768; ++ci) acc += swint[ci * 64 + p] * w[co * 768 + ci];
  out[co * 64 + p] = acc;
}

// deconv 4x4 stride2 pad2 + bias + relu, f32 in (S=8), packed-bf16 out
template <int S>
__global__ __launch_bounds__(256) void k_deconv(const float* __restrict__ x,
                                                const float* __restrict__ w,
                                                const float* __restrict__ bias,
                                                unsigned short* __restrict__ yp) {
  const int SO = 2 * S;
  const int TX = SO / 16;
  int co = blockIdx.y;
  int tile = blockIdx.x;
  int ty0 = (tile / TX) * 16, tx0 = (tile % TX) * 16;
  int t = threadIdx.x;
  int ly = t >> 4, lx = t & 15;
  int oy = ty0 + ly, ox = tx0 + lx;
  int iyb = (ty0 >> 1) - 1, ixb = (tx0 >> 1) - 1;
  int p = oy & 1, q = ox & 1;
  int iyA = ((oy + p - 2) >> 1) - iyb;
  int ixA = ((ox + q - 2) >> 1) - ixb;
  int i00 = (3 - p) * 4 + (3 - q);
  int i01 = (3 - p) * 4 + (1 - q);
  int i10 = (1 - p) * 4 + (3 - q);
  int i11 = (1 - p) * 4 + (1 - q);
  __shared__ float lx_s[8][10][10];
  __shared__ float lw_s[8][16];
  float acc = bias[co];
  for (int c0 = 0; c0 < CCH; c0 += 8) {
    __syncthreads();
    for (int i = t; i < 800; i += 256) {
      int u = i / 100, rem = i % 100;
      int r = rem / 10, c = rem % 10;
      int gy = iyb + r, gx = ixb + c;
      float v = 0.f;
      if (gy >= 0 && gy < S && gx >= 0 && gx < S)
        v = x[(size_t)(c0 + u) * S * S + gy * S + gx];
      lx_s[u][r][c] = v;
    }
    if (t < 128) {
      int u = t >> 4, e = t & 15;
      lw_s[u][e] = w[(size_t)(c0 + u) * 4096 + co * 16 + e];
    }
    __syncthreads();
#pragma unroll
    for (int u = 0; u < 8; ++u) {
      acc += lx_s[u][iyA][ixA]     * lw_s[u][i00]
           + lx_s[u][iyA][ixA + 1] * lw_s[u][i01]
           + lx_s[u][iyA + 1][ixA]     * lw_s[u][i10]
           + lx_s[u][iyA + 1][ixA + 1] * lw_s[u][i11];
    }
  }
  acc = fmaxf(acc, 0.f);
  yp[((size_t)(co >> 1) * SO * SO + (size_t)oy * SO + ox) * 2 + (co & 1)] = f2bf(acc);
}

// pack conv3 weights (4 layers): [co][ci][9] f32 -> bf16 [tap][co][ci]
__global__ void k_packc3(const float* __restrict__ w, short* __restrict__ wpk) {
  int layer = blockIdx.y;
  const float* wl = w + (size_t)layer * 589824;
  short* wo = wpk + (size_t)layer * 589824;
  int co = blockIdx.x, ci = threadIdx.x;
  for (int tap = 0; tap < 9; ++tap)
    wo[((size_t)(tap * 256 + co) * 256) + ci] = (short)f2bf(wl[((size_t)(co * 256 + ci)) * 9 + tap]);
}

// pack deconv weights (layers 1..4): [ci][co][4][4] f32 -> bf16 [pq][tt][co][ci]
__global__ void k_packdc(const float* __restrict__ w, short* __restrict__ wpk) {
  int layer = blockIdx.y;
  const float* wl = w + (size_t)(layer + 1) * 1048576;
  int co = blockIdx.x, ci = threadIdx.x;
  for (int pq = 0; pq < 4; ++pq) {
    int p = pq >> 1, q = pq & 1;
    for (int tt = 0; tt < 4; ++tt) {
      int dyi = tt >> 1, dxi = tt & 1;
      int wr = dyi ? (1 - p) : (3 - p);
      int wc = dxi ? (1 - q) : (3 - q);
      wpk[((size_t)layer * 1048576) + ((size_t)((pq * 4 + tt) * 256 + co) * 256) + ci] =
          (short)f2bf(wl[((size_t)(ci * 256 + co)) * 16 + wr * 4 + wc]);
    }
  }
}

// pack stage-5 conv weights: wB[co][c*288 + e*32 + cl] = w[co][(c*32+cl)*9 + e], bf16
__global__ void k_packc5(const float* __restrict__ w, short* __restrict__ wB) {
  int co = blockIdx.x;
  for (int kk = threadIdx.x; kk < 2304; kk += 256) {
    int c = kk / 288, r = kk % 288;
    int e = r >> 5, cl = r & 31;
    wB[(size_t)co * 2304 + kk] = (short)f2bf(w[(size_t)co * 2304 + (size_t)(c * 32 + cl) * 9 + e]);
  }
}

// MFMA conv3x3 pad1 + bias, O rows x CW=S/CSP cols per block; weights direct-global.
template <int S, int O, int CSP>
__global__ __launch_bounds__(256) void k_conv3u(const unsigned* __restrict__ xp,
                                                const short* __restrict__ wpk,
                                                const float* __restrict__ bias,
                                                unsigned* __restrict__ yp) {
  constexpr int CW = S / CSP;
  constexpr int WPC = (CW >= 64) ? 2 : 1;
  constexpr int WCO = 4 / WPC;
  constexpr int COS = 64 / WCO;
  constexpr int MR = COS / 16;
  constexpr int PSP = CW / WPC;
  constexpr int NR = PSP / 16;
  constexpr int CBK = (CW + 2 + 31) / 32;
  constexpr int RS = O + 2;
  __shared__ short x_s[RS * (CW + 2) * PCI];
  unsigned* x_s32 = (unsigned*)x_s;
  int t = threadIdx.x, l = t & 63, wv = t >> 6;
  int wcob = (wv % WCO) * COS;
  int wposb = (wv / WCO) * PSP;
  int row0 = blockIdx.x * O;
  int co0 = blockIdx.y * 64;
  int col0 = blockIdx.z * CW;
  int colb = t & 31, ci2b = t >> 5;
  f32x4 acc[O][MR][NR];
#pragma unroll
  for (int o = 0; o < O; ++o)
#pragma unroll
    for (int m = 0; m < MR; ++m)
#pragma unroll
      for (int n = 0; n < NR; ++n) { f32x4 z = {0.f, 0.f, 0.f, 0.f}; acc[o][m][n] = z; }
  for (int c0 = 0; c0 < CCH; c0 += 32) {
    int cb = c0 >> 1;
    __syncthreads();
#pragma unroll
    for (int r = 0; r < RS; ++r) {
      int gy = row0 - 1 + r;
      bool yok = (gy >= 0 && gy < S);
#pragma unroll
      for (int cbk = 0; cbk < CBK; ++cbk) {
        int col = colb + cbk * 32;
        if (col < CW + 2) {
          int gx = col0 + col - 1;
          bool ok = yok && (gx >= 0) && (gx < S);
          unsigned v0 = 0, v1 = 0;
          if (ok) {
            size_t gbase = (size_t)(cb + ci2b) * S * S + (size_t)gy * S + gx;
            v0 = xp[gbase];
            v1 = xp[gbase + (size_t)8 * S * S];
          }
          int lb = (r * (CW + 2) + col) * (PCI / 2);
          x_s32[lb + ci2b] = v0;
          x_s32[lb + ci2b + 8] = v1;
        }
      }
    }
    __syncthreads();
#pragma unroll
    for (int dyg = 0; dyg < 3; ++dyg)
#pragma unroll
      for (int dx = 0; dx < 3; ++dx) {
        short8 a[MR];
#pragma unroll
        for (int m = 0; m < MR; ++m)
          a[m] = *(const short8*)&wpk[((size_t)((dyg * 3 + dx) * 256 + co0 + wcob + m * 16 + (l & 15)) * 256) + c0 + (l >> 4) * 8];
#pragma unroll
        for (int o = 0; o < O; ++o) {
          short8 b[NR];
#pragma unroll
          for (int n = 0; n < NR; ++n)
            b[n] = *(const short8*)&x_s[((dyg + o) * (CW + 2) + wposb + n * 16 + (l & 15) + dx) * PCI + (l >> 4) * 8];
#pragma unroll
          for (int m = 0; m < MR; ++m)
#pragma unroll
            for (int n = 0; n < NR; ++n) mfma_bf16(acc[o][m][n], a[m], b[n]);
        }
      }
  }
  asm volatile("s_nop 7\n\ts_nop 7" ::);
#pragma unroll
  for (int o = 0; o < O; ++o)
#pragma unroll
    for (int m = 0; m < MR; ++m)
#pragma unroll
      for (int n = 0; n < NR; ++n) {
        int cob = co0 + wcob + m * 16 + (l >> 4) * 4;
        int px = col0 + wposb + n * 16 + (l & 15);
#pragma unroll
        for (int r4p = 0; r4p < 2; ++r4p) {
          unsigned pk = (unsigned)f2bf(acc[o][m][n][2 * r4p] + bias[cob + 2 * r4p])
                      | ((unsigned)f2bf(acc[o][m][n][2 * r4p + 1] + bias[cob + 2 * r4p + 1]) << 16);
          yp[(size_t)((cob >> 1) + r4p) * S * S + (size_t)(row0 + o) * S + px] = pk;
        }
      }
}

// MFMA deconv4x4 s2 p2 + bias + relu, O rows x CW cols, both q parities per block.
// blockIdx.z = p + 2*cx. Weights direct-global.
template <int S, int O, int CSP>
__global__ __launch_bounds__(256) void k_deconvu(const unsigned* __restrict__ xp,
                                                 const short* __restrict__ wpk,
                                                 const float* __restrict__ bias,
                                                 unsigned* __restrict__ yp) {
  constexpr int CW = S / CSP;
  constexpr int WPC = (CW >= 64) ? 2 : 1;
  constexpr int WCO = 4 / WPC;
  constexpr int COS = 64 / WCO;
  constexpr int MR = COS / 16;
  constexpr int PSP = CW / WPC;
  constexpr int NR = PSP / 16;
  constexpr int CBK = (CW + 2 + 31) / 32;
  constexpr int RS = O + 1;
  const int SO = 2 * S;
  __shared__ short x_s[RS * (CW + 2) * PCI];
  unsigned* x_s32 = (unsigned*)x_s;
  int t = threadIdx.x, l = t & 63, wv = t >> 6;
  int wcob = (wv % WCO) * COS;
  int wposb = (wv / WCO) * PSP;
  int row0 = blockIdx.x * O;
  int co0 = blockIdx.y * 64;
  int p = blockIdx.z & 1;
  int col0 = (blockIdx.z >> 1) * CW;
  int colb = t & 31, ci2b = t >> 5;
  f32x4 acc[2][O][MR][NR];
#pragma unroll
  for (int q = 0; q < 2; ++q)
#pragma unroll
    for (int o = 0; o < O; ++o)
#pragma unroll
      for (int m = 0; m < MR; ++m)
#pragma unroll
        for (int n = 0; n < NR; ++n) { f32x4 z = {0.f, 0.f, 0.f, 0.f}; acc[q][o][m][n] = z; }
  for (int c0 = 0; c0 < CCH; c0 += 32) {
    int cb = c0 >> 1;
    __syncthreads();
#pragma unroll
    for (int r = 0; r < RS; ++r) {
      int gy = row0 + p - 1 + r;
      bool yok = (gy >= 0 && gy < S);
#pragma unroll
      for (int cbk = 0; cbk < CBK; ++cbk) {
        int col = colb + cbk * 32;
        if (col < CW + 2) {
          int gx = col0 + col - 1;
          bool ok = yok && (gx >= 0) && (gx < S);
          unsigned v0 = 0, v1 = 0;
          if (ok) {
            size_t gbase = (size_t)(cb + ci2b) * S * S + (size_t)gy * S + gx;
            v0 = xp[gbase];
            v1 = xp[gbase + (size_t)8 * S * S];
          }
          int lb = (r * (CW + 2) + col) * (PCI / 2);
          x_s32[lb + ci2b] = v0;
          x_s32[lb + ci2b + 8] = v1;
        }
      }
    }
    __syncthreads();
#pragma unroll
    for (int dyi = 0; dyi < 2; ++dyi)
#pragma unroll
      for (int o = 0; o < O; ++o) {
        short8 b[3][NR];
#pragma unroll
        for (int off = 0; off < 3; ++off)
#pragma unroll
          for (int n = 0; n < NR; ++n)
            b[off][n] = *(const short8*)&x_s[((dyi + o) * (CW + 2) + wposb + n * 16 + (l & 15) + off) * PCI + (l >> 4) * 8];
#pragma unroll
        for (int q = 0; q < 2; ++q)
#pragma unroll
          for (int dxi = 0; dxi < 2; ++dxi) {
            int c8 = (2 * p + q) * 4 + dyi * 2 + dxi;
            short8 a[MR];
#pragma unroll
            for (int m = 0; m < MR; ++m)
              a[m] = *(const short8*)&wpk[((size_t)(c8 * 256 + co0 + wcob + m * 16 + (l & 15)) * 256) + c0 + (l >> 4) * 8];
#pragma unroll
            for (int m = 0; m < MR; ++m)
#pragma unroll
              for (int n = 0; n < NR; ++n) mfma_bf16(acc[q][o][m][n], a[m], b[dxi + q][n]);
          }
      }
  }
  asm volatile("s_nop 7\n\ts_nop 7" ::);
#pragma unroll
  for (int o = 0; o < O; ++o) {
    int oy = 2 * (row0 + o) + p;
#pragma unroll
    for (int m = 0; m < MR; ++m)
#pragma unroll
      for (int n = 0; n < NR; ++n) {
        int px = col0 + wposb + n * 16 + (l & 15);
#pragma unroll
        for (int r4p = 0; r4p < 2; ++r4p) {
          int cob = co0 + wcob + m * 16 + (l >> 4) * 4 + 2 * r4p;
          float b0 = bias[cob], b1 = bias[cob + 1];
          unsigned pk0 = (unsigned)f2bf(fmaxf(acc[0][o][m][n][2 * r4p] + b0, 0.f))
                       | ((unsigned)f2bf(fmaxf(acc[0][o][m][n][2 * r4p + 1] + b1, 0.f)) << 16);
          unsigned pk1 = (unsigned)f2bf(fmaxf(acc[1][o][m][n][2 * r4p] + b0, 0.f))
                       | ((unsigned)f2bf(fmaxf(acc[1][o][m][n][2 * r4p + 1] + b1, 0.f)) << 16);
          uint2 pk = make_uint2(pk0, pk1);
          *(uint2*)&yp[(size_t)(cob >> 1) * SO * SO + (size_t)oy * SO + 2 * px] = pk;
        }
      }
  }
}

// sparse final conv3 via MFMA. out[j][co] = sum_k A[j][k]*wB[co][k] + bias[co].
__global__ __launch_bounds__(256) void k_conv3sM(const unsigned* __restrict__ xp,
                                                 const short* __restrict__ wB,
                                                 const float* __restrict__ bias,
                                                 const int* __restrict__ idx,
                                                 float* __restrict__ out) {
  __shared__ short a_s[16][296];
  __shared__ int py_s[16], px_s[16];
  int t = threadIdx.x, l = t & 63, wv = t >> 6;
  int j0 = blockIdx.x * 16;
  int co0 = blockIdx.y * 128 + wv * 32;
  if (t < 16) {
    int p = idx[j0 + t];
    py_s[t] = p >> 8;
    px_s[t] = p & 255;
  }
  f32x4 acc[2];
  { f32x4 z = {0.f, 0.f, 0.f, 0.f}; acc[0] = z; acc[1] = z; }
  for (int c = 0; c < 8; ++c) {
    __syncthreads();
    for (int i = t; i < 2304; i += 256) {
      int ci2 = i & 15;
      int je = i >> 4;
      int j = je / 9, e = je % 9;
      int gy = py_s[j] - 1 + e / 3, gx = px_s[j] - 1 + e % 3;
      unsigned v = 0;
      if (gy >= 0 && gy < 256 && gx >= 0 && gx < 256)
        v = xp[(size_t)(c * 16 + ci2) * HWP + gy * 256 + gx];
      *(unsigned*)&a_s[j][e * 32 + 2 * ci2] = v;
    }
    __syncthreads();
#pragma unroll
    for (int s = 0; s < 9; ++s) {
      short8 a = *(const short8*)&a_s[l & 15][s * 32 + (l >> 4) * 8];
      int kg = c * 288 + s * 32 + (l >> 4) * 8;
      short8 b0 = *(const short8*)&wB[(size_t)(co0 + (l & 15)) * 2304 + kg];
      short8 b1 = *(const short8*)&wB[(size_t)(co0 + 16 + (l & 15)) * 2304 + kg];
      mfma_bf16(acc[0], a, b0);
      mfma_bf16(acc[1], a, b1);
    }
  }
  asm volatile("s_nop 7\n\ts_nop 7" ::);
#pragma unroll
  for (int n = 0; n < 2; ++n)
#pragma unroll
    for (int r = 0; r < 4; ++r) {
      int j = j0 + (l >> 4) * 4 + r;
      int co = co0 + n * 16 + (l & 15);
      out[(size_t)j * 256 + co] = acc[n][r] + bias[co];
    }
}

// fused: passthrough copy of down into out + gate keys
__global__ void k_gatecopy(const float* __restrict__ down, const float* __restrict__ gw,
                           float* __restrict__ out, unsigned int* __restrict__ keys) {
  int p = blockIdx.x * 256 + threadIdx.x;
  float acc = 0.f;
  for (int c = 0; c < CCH; ++c) {
    float v = down[(size_t)c * HWP + p];
    out[(size_t)c * HWP + p] = v;
    acc += v * gw[c];
  }
  unsigned int u = __float_as_uint(acc);
  keys[p] = (u & 0x80000000u) ? ~u : (u | 0x80000000u);
}

__global__ void k_hist(const unsigned int* __restrict__ keys, unsigned int* hist,
                       const SelState* st, int r) {
  __shared__ unsigned int lh[256];
  int t = threadIdx.x;
  lh[t] = 0;
  __syncthreads();
  unsigned int key = keys[blockIdx.x * 256 + t];
  bool ok = (r == 0) || ((key >> (32 - 8 * r)) == st->P);
  if (ok) atomicAdd(&lh[(key >> (24 - 8 * r)) & 255u], 1u);
  __syncthreads();
  if (lh[t]) atomicAdd(&hist[t], lh[t]);
}

__global__ void k_scan(unsigned int* hist, SelState* st) {
  if (threadIdx.x == 0) {
    int need = st->kneed;
    unsigned int cum = 0;
    for (int b = 255; b >= 0; --b) {
      unsigned int h = hist[b];
      if (cum + h >= (unsigned int)need) {
        st->P = (st->P << 8) | (unsigned int)b;
        st->kneed = need - (int)cum;
        break;
      }
      cum += h;
    }
  }
  __syncthreads();
  hist[threadIdx.x] = 0;
}

__global__ void k_compact(const unsigned int* __restrict__ keys, SelState* st,
                          int* __restrict__ idx, int* __restrict__ eq) {
  int p = blockIdx.x * 256 + threadIdx.x;
  unsigned int key = keys[p];
  unsigned int P = st->P;
  if (key > P) {
    int pos = atomicAdd(&st->nGreater, 1);
    idx[pos] = p;
  } else if (key == P) {
    int e = atomicAdd(&st->nEqual, 1);
    if (e < 4096) eq[e] = p;
  }
}

__global__ void k_finalize(SelState* st, int* idx, int* eq) {
  if (threadIdx.x != 0) return;
  int n = st->nEqual;
  if (n > 4096) n = 4096;
  for (int i = 1; i < n; ++i) {
    int v = eq[i], j = i - 1;
    while (j >= 0 && eq[j] > v) { eq[j + 1] = eq[j]; --j; }
    eq[j + 1] = v;
  }
  int g = st->nGreater;
  for (int i = 0; i < st->kneed; ++i) idx[g + i] = eq[i];
}

__global__ void k_transpose(const float* __restrict__ in, float* __restrict__ out, int rows) {
  int o = blockIdx.x, c = threadIdx.x;
  out[(size_t)c * rows + o] = in[(size_t)o * 256 + c];
}

// gather rows at idx, project to Q,K,V, emit bf16 Qb/Kb[h][q][d] and Vt[h][d][q]
__global__ __launch_bounds__(256) void k_qkv2(const float* __restrict__ down,
                                              const float* __restrict__ srows,
                                              const int* __restrict__ idx,
                                              const float* __restrict__ wT,
                                              const float* __restrict__ bias,
                                              short* __restrict__ Qb,
                                              short* __restrict__ Kb,
                                              short* __restrict__ Vt) {
  __shared__ float xq[4][256], xk[4][256];
  int j0 = blockIdx.x * 4;
  int c = threadIdx.x;
  for (int r = 0; r < 4; ++r) {
    int p = idx[j0 + r];
    xq[r][c] = down[(size_t)c * HWP + p];
    xk[r][c] = srows[(size_t)(j0 + r) * 256 + c];
  }
  __syncthreads();
  float aq[4], ak[4], av[4];
#pragma unroll
  for (int r = 0; r < 4; ++r) {
    aq[r] = bias[c]; ak[r] = bias[256 + c]; av[r] = bias[512 + c];
  }
  for (int i = 0; i < 256; ++i) {
    float wq = wT[i * 768 + c];
    float wk = wT[i * 768 + 256 + c];
    float wv = wT[i * 768 + 512 + c];
#pragma unroll
    for (int r = 0; r < 4; ++r) {
      float xv = xq[r][i], kv = xk[r][i];
      aq[r] += xv * wq;
      ak[r] += kv * wk;
      av[r] += kv * wv;
    }
  }
  int h = c >> 5, d = c & 31;
#pragma unroll
  for (int r = 0; r < 4; ++r) {
    int j = j0 + r;
    Qb[((size_t)h * 2048 + j) * 32 + d] = (short)f2bf(aq[r]);
    Kb[((size_t)h * 2048 + j) * 32 + d] = (short)f2bf(ak[r]);
    Vt[((size_t)h * 32 + d) * 2048 + j] = (short)f2bf(av[r]);
  }
}

// fused flash attention: QK^T -> online softmax -> PV. grid (32 qtiles, 8 h), 4 waves.
__global__ __launch_bounds__(256) void k_fattn(const short* __restrict__ Qb,
                                               const short* __restrict__ Kb,
                                               const short* __restrict__ Vt,
                                               float* __restrict__ Oa) {
  __shared__ short P_lds[4][16][136];
  int t = threadIdx.x, l = t & 63, wv = t >> 6;
  int h = blockIdx.y;
  int q0 = blockIdx.x * 64 + wv * 16;
  const short* Qh = Qb + (size_t)h * 2048 * 32;
  const short* Kh = Kb + (size_t)h * 2048 * 32;
  const short* Vh = Vt + (size_t)h * 32 * 2048;
  short8 a_q = *(const short8*)&Qh[(size_t)(q0 + (l & 15)) * 32 + (l >> 4) * 8];
  f32x4 o0 = {0.f, 0.f, 0.f, 0.f}, o1 = {0.f, 0.f, 0.f, 0.f};
  float m_run[4], l_run[4];
#pragma unroll
  for (int r = 0; r < 4; ++r) { m_run[r] = -3e38f; l_run[r] = 0.f; }
  const float scale = 0.17677669529663687f;
  for (int k0 = 0; k0 < 2048; k0 += 128) {
    f32x4 s[8];
#pragma unroll
    for (int kt = 0; kt < 8; ++kt) {
      f32x4 z = {0.f, 0.f, 0.f, 0.f};
      s[kt] = z;
      short8 b = *(const short8*)&Kh[(size_t)(k0 + kt * 16 + (l & 15)) * 32 + (l >> 4) * 8];
      mfma_bf16(s[kt], a_q, b);
    }
    asm volatile("s_nop 7\n\ts_nop 7" ::);
    float tm[4];
#pragma unroll
    for (int r = 0; r < 4; ++r) {
      float mx = s[0][r];
#pragma unroll
      for (int kt = 1; kt < 8; ++kt) mx = fmaxf(mx, s[kt][r]);
      tm[r] = mx * scale;
    }
#pragma unroll
    for (int mask = 1; mask < 16; mask <<= 1)
#pragma unroll
      for (int r = 0; r < 4; ++r) tm[r] = fmaxf(tm[r], __shfl_xor(tm[r], mask));
    float mn[4], al[4], rs[4];
#pragma unroll
    for (int r = 0; r < 4; ++r) {
      mn[r] = fmaxf(m_run[r], tm[r]);
      al[r] = __expf(m_run[r] - mn[r]);
      rs[r] = 0.f;
    }
#pragma unroll
    for (int kt = 0; kt < 8; ++kt)
#pragma unroll
      for (int r = 0; r < 4; ++r) {
        float pv = __expf(s[kt][r] * scale - mn[r]);
        s[kt][r] = pv;
        rs[r] += pv;
      }
#pragma unroll
    for (int mask = 1; mask < 16; mask <<= 1)
#pragma unroll
      for (int r = 0; r < 4; ++r) rs[r] += __shfl_xor(rs[r], mask);
#pragma unroll
    for (int r = 0; r < 4; ++r) {
      l_run[r] = l_run[r] * al[r] + rs[r];
      m_run[r] = mn[r];
      o0[r] *= al[r];
      o1[r] *= al[r];
    }
#pragma unroll
    for (int kt = 0; kt < 8; ++kt)
#pragma unroll
      for (int r = 0; r < 4; ++r)
        P_lds[wv][(l >> 4) * 4 + r][kt * 16 + (l & 15)] = (short)f2bf(s[kt][r]);
#pragma unroll
    for (int kc = 0; kc < 4; ++kc) {
      short8 ap = *(const short8*)&P_lds[wv][l & 15][kc * 32 + (l >> 4) * 8];
      short8 b0 = *(const short8*)&Vh[(size_t)(l & 15) * 2048 + k0 + kc * 32 + (l >> 4) * 8];
      short8 b1 = *(const short8*)&Vh[(size_t)(16 + (l & 15)) * 2048 + k0 + kc * 32 + (l >> 4) * 8];
      mfma_bf16(o0, ap, b0);
      mfma_bf16(o1, ap, b1);
    }
  }
  asm volatile("s_nop 7\n\ts_nop 7" ::);
#pragma unroll
  for (int r = 0; r < 4; ++r) {
    float inv = 1.f / l_run[r];
    int qr = q0 + (l >> 4) * 4 + r;
    Oa[(size_t)qr * 256 + h * 32 + (l & 15)] = o0[r] * inv;
    Oa[(size_t)qr * 256 + h * 32 + 16 + (l & 15)] = o1[r] * inv;
  }
}

// out-projection (8 rows/block) fused with scatter into final output columns
__global__ __launch_bounds__(256) void k_outproj8(const float* __restrict__ Oa,
                                                  const float* __restrict__ owT,
                                                  const float* __restrict__ ob,
                                                  const int* __restrict__ idx,
                                                  float* __restrict__ out) {
  __shared__ float xo[8][256];
  int j0 = blockIdx.x * 8;
  int c = threadIdx.x;
  for (int r = 0; r < 8; ++r) xo[r][c] = Oa[(size_t)(j0 + r) * 256 + c];
  __syncthreads();
  float a[8];
#pragma unroll
  for (int r = 0; r < 8; ++r) a[r] = ob[c];
  for (int i = 0; i < 256; ++i) {
    float wv = owT[i * 256 + c];
#pragma unroll
    for (int r = 0; r < 8; ++r) a[r] += xo[r][i] * wv;
  }
#pragma unroll
  for (int r = 0; r < 8; ++r) out[(size_t)c * HWP + idx[j0 + r]] = a[r];
}

extern "C" void kernel_launch(void* const* d_in, const int* in_sizes, int n_in,
                              void* d_out, int out_size, void* d_ws, size_t ws_size,
                              hipStream_t stream) {
  const float* down  = (const float*)d_in[0];
  const float* swint = (const float*)d_in[1];
  const float* wt_w  = (const float*)d_in[2];
  const float* wt_b  = (const float*)d_in[3];
  const float* up_dw = (const float*)d_in[4];
  const float* up_db = (const float*)d_in[5];
  const float* up_cw = (const float*)d_in[6];
  const float* up_cb = (const float*)d_in[7];
  const float* gate_w = (const float*)d_in[8];
  const float* in_w  = (const float*)d_in[10];
  const float* in_b  = (const float*)d_in[11];
  const float* out_w = (const float*)d_in[12];
  const float* out_b = (const float*)d_in[13];
  float* out = (float*)d_out;
  char* ws = (char*)d_ws;

  float* bufA = (float*)ws;
  unsigned* actA = (unsigned*)ws;
  unsigned* actB = (unsigned*)(ws + BUF_B_OFF);
  unsigned int* keys = (unsigned int*)(ws + KEYS_OFF);
  unsigned int* hist = (unsigned int*)(ws + HIST_OFF);
  SelState* st = (SelState*)(ws + STATE_OFF);
  int* idx = (int*)(ws + IDX_OFF);
  int* eq = (int*)(ws + EQ_OFF);
  float* Oa = (float*)(ws + OA_OFF);
  float* wTi = (float*)(ws + WTI_OFF);
  float* wTo = (float*)(ws + WTO_OFF);
  float* srows = (float*)(ws + SROWS_OFF);
  short* wB5 = (short*)(ws + WT5_OFF);
  short* Qb = (short*)(ws + QB_OFF);
  short* Kb = (short*)(ws + KB_OFF);
  short* Vt = (short*)(ws + VT_OFF);
  short* cpk = (short*)(ws + CPK_OFF);
  short* dpk = (short*)(ws + DPK_OFF);

  k_init<<<1, 256, 0, stream>>>(hist, st);

  // fused gate + passthrough copy, then exact top-k (radix select)
  k_gatecopy<<<256, 256, 0, stream>>>(down, gate_w, out, keys);
  for (int r = 0; r < 4; ++r) {
    k_hist<<<256, 256, 0, stream>>>(keys, hist, st, r);
    k_scan<<<1, 256, 0, stream>>>(hist, st);
  }
  k_compact<<<256, 256, 0, stream>>>(keys, st, idx, eq);
  k_finalize<<<1, 64, 0, stream>>>(st, idx, eq);

  // weight packs (batched over layers)
  k_packc3<<<dim3(256, 4), 256, 0, stream>>>(up_cw, cpk);
  k_packdc<<<dim3(256, 4), 256, 0, stream>>>(up_dw, dpk);
  k_packc5<<<256, 256, 0, stream>>>(up_cw + 2359296, wB5);

  // upsampler chain: MFMA bf16 implicit-GEMM, packed-bf16 activations (A/B ping-pong)
  k_wtconv<<<256, 64, 0, stream>>>(swint, wt_w, wt_b, bufA);
  k_deconv<8><<<dim3(1, 256), 256, 0, stream>>>(bufA, up_dw, up_db, (unsigned short*)actB);
  k_conv3u<16, 2, 1><<<dim3(8, 4, 1), 256, 0, stream>>>(actB, cpk, up_cb, actA);
  k_deconvu<16, 2, 1><<<dim3(8, 4, 2), 256, 0, stream>>>(actA, dpk, up_db + 256, actB);
  k_conv3u<32, 2, 1><<<dim3(16, 4, 1), 256, 0, stream>>>(actB, cpk + 589824, up_cb + 256, actA);
  k_deconvu<32, 2, 1><<<dim3(16, 4, 2), 256, 0, stream>>>(actA, dpk + 1048576, up_db + 512, actB);
  k_conv3u<64, 1, 2><<<dim3(64, 4, 2), 256, 0, stream>>>(actB, cpk + 2 * 589824, up_cb + 512, actA);
  k_deconvu<64, 1, 2><<<dim3(64, 4, 4), 256, 0, stream>>>(actA, dpk + 2 * 1048576, up_db + 768, actB);
  k_conv3u<128, 1, 2><<<dim3(128, 4, 2), 256, 0, stream>>>(actB, cpk + 3 * 589824, up_cb + 768, actA);
  k_deconvu<128, 1, 2><<<dim3(128, 4, 4), 256, 0, stream>>>(actA, dpk + 3 * 1048576, up_db + 1024, actB);

  // in/out projection transposed weights
  k_transpose<<<768, 256, 0, stream>>>(in_w, wTi, 768);
  k_transpose<<<256, 256, 0, stream>>>(out_w, wTo, 256);

  // final conv3 via MFMA at the 2048 gathered positions (reads packed actB)
  k_conv3sM<<<dim3(128, 2), 256, 0, stream>>>(actB, wB5, up_cb + 1024, idx, srows);

  // attention path: bf16 QKV, fused flash attention, out-projection
  k_qkv2<<<512, 256, 0, stream>>>(down, srows, idx, wTi, in_b, Qb, Kb, Vt);
  k_fattn<<<dim3(32, 8), 256, 0, stream>>>(Qb, Kb, Vt, Oa);
  k_outproj8<<<256, 256, 0, stream>>>(Oa, wTo, out_b, idx, out);
}

// Round 13
// 693.676 us; speedup vs baseline: 1.0728x; 1.0728x over previous
//
#include <hip/hip_runtime.h>
#include <math.h>

#define CCH 256
#define HWP 65536
#define PCI 40   // padded ci stride (shorts) in LDS

typedef short short8 __attribute__((ext_vector_type(8)));
typedef float f32x4 __attribute__((ext_vector_type(4)));
typedef unsigned short us4 __attribute__((ext_vector_type(4)));

__device__ inline unsigned short f2bf(float f) {
  unsigned u = __float_as_uint(f);
  return (unsigned short)((u + 0x7FFFu + ((u >> 16) & 1u)) >> 16);
}
__device__ inline float bf2f(unsigned short s) {
  return __uint_as_float(((unsigned)s) << 16);
}

__device__ inline void mfma_bf16(f32x4& d, short8 a, short8 b) {
  asm volatile("v_mfma_f32_16x16x32_bf16 %0, %1, %2, %0" : "+v"(d) : "v"(a), "v"(b));
}

// ---- ws layout (bytes) ----
static const size_t BUF_B_OFF = 67108864;        // actA @0, actB @64MB
static const size_t TAIL_OFF  = 134217728;
static const size_t KEYS_OFF  = TAIL_OFF;
static const size_t HIST_OFF  = TAIL_OFF + 262144;
static const size_t STATE_OFF = TAIL_OFF + 263168;
static const size_t IDX_OFF   = TAIL_OFF + 263424;
static const size_t EQ_OFF    = TAIL_OFF + 271616;
// overlays in bufA region (chain activations use [0, 8.4MB)):
static const size_t OB_OFF    = 6291456;         // bf16 attn out 2048*256*2 (written post-chain)
static const size_t WBI_OFF   = 8388608;         // bf16 in_w pack 768*256*2
static const size_t WBO_OFF   = 9437184;         // bf16 out_w pack 256*256*2
static const size_t SROWS_OFF = 10485760;        // bf16 srows 2048*256*2
static const size_t DQ_OFF    = 12582912;        // bf16 gathered down rows 2048*256*2
static const size_t GPART_OFF = 16777216;        // f32 gate partials 8*65536*4 = 2MB
static const size_t WT5_OFF   = 20971520;        // bf16 wB5[256][2304]
static const size_t QB_OFF    = 31457280;
static const size_t KB_OFF    = 32505856;
static const size_t VT_OFF    = 33554432;
static const size_t CPK_OFF   = 37748736;
static const size_t DPK_OFF   = 44040192;

struct SelState { unsigned int P; int kneed; int nGreater; int nEqual; };

__global__ void k_init(unsigned int* hist, SelState* st) {
  int t = threadIdx.x;
  hist[t] = 0;
  if (t == 0) { st->P = 0u; st->kneed = 2048; st->nGreater = 0; st->nEqual = 0; }
}

// 1x1 conv 768->256 on 8x8
__global__ void k_wtconv(const float* __restrict__ swint, const float* __restrict__ w,
                         const float* __restrict__ b, float* __restrict__ out) {
  int co = blockIdx.x, p = threadIdx.x;
  float acc = b[co];
  for (int ci = 0; ci < 768; ++ci) acc += swint[ci * 64 + p] * w[co * 768 + ci];
  out[co * 64 + p] = acc;
}

// deconv 4x4 stride2 pad2 + bias + relu, f32 in (S=8), packed-bf16 out
template <int S>
__global__ __launch_bounds__(256) void k_deconv(const float* __restrict__ x,
                                                const float* __restrict__ w,
                                                const float* __restrict__ bias,
                                                unsigned short* __restrict__ yp) {
  const int SO = 2 * S;
  const int TX = SO / 16;
  int co = blockIdx.y;
  int tile = blockIdx.x;
  int ty0 = (tile / TX) * 16, tx0 = (tile % TX) * 16;
  int t = threadIdx.x;
  int ly = t >> 4, lx = t & 15;
  int oy = ty0 + ly, ox = tx0 + lx;
  int iyb = (ty0 >> 1) - 1, ixb = (tx0 >> 1) - 1;
  int p = oy & 1, q = ox & 1;
  int iyA = ((oy + p - 2) >> 1) - iyb;
  int ixA = ((ox + q - 2) >> 1) - ixb;
  int i00 = (3 - p) * 4 + (3 - q);
  int i01 = (3 - p) * 4 + (1 - q);
  int i10 = (1 - p) * 4 + (3 - q);
  int i11 = (1 - p) * 4 + (1 - q);
  __shared__ float lx_s[8][10][10];
  __shared__ float lw_s[8][16];
  float acc = bias[co];
  for (int c0 = 0; c0 < CCH; c0 += 8) {
    __syncthreads();
    for (int i = t; i < 800; i += 256) {
      int u = i / 100, rem = i % 100;
      int r = rem / 10, c = rem % 10;
      int gy = iyb + r, gx = ixb + c;
      float v = 0.f;
      if (gy >= 0 && gy < S && gx >= 0 && gx < S)
        v = x[(size_t)(c0 + u) * S * S + gy * S + gx];
      lx_s[u][r][c] = v;
    }
    if (t < 128) {
      int u = t >> 4, e = t & 15;
      lw_s[u][e] = w[(size_t)(c0 + u) * 4096 + co * 16 + e];
    }
    __syncthreads();
#pragma unroll
    for (int u = 0; u < 8; ++u) {
      acc += lx_s[u][iyA][ixA]     * lw_s[u][i00]
           + lx_s[u][iyA][ixA + 1] * lw_s[u][i01]
           + lx_s[u][iyA + 1][ixA]     * lw_s[u][i10]
           + lx_s[u][iyA + 1][ixA + 1] * lw_s[u][i11];
    }
  }
  acc = fmaxf(acc, 0.f);
  yp[((size_t)(co >> 1) * SO * SO + (size_t)oy * SO + ox) * 2 + (co & 1)] = f2bf(acc);
}

// pack conv3 weights (4 layers): [co][ci][9] f32 -> bf16 [tap][co][ci]
__global__ void k_packc3(const float* __restrict__ w, short* __restrict__ wpk) {
  int layer = blockIdx.y;
  const float* wl = w + (size_t)layer * 589824;
  short* wo = wpk + (size_t)layer * 589824;
  int co = blockIdx.x, ci = threadIdx.x;
  for (int tap = 0; tap < 9; ++tap)
    wo[((size_t)(tap * 256 + co) * 256) + ci] = (short)f2bf(wl[((size_t)(co * 256 + ci)) * 9 + tap]);
}

// pack deconv weights (layers 1..4): [ci][co][4][4] f32 -> bf16 [pq][tt][co][ci]
__global__ void k_packdc(const float* __restrict__ w, short* __restrict__ wpk) {
  int layer = blockIdx.y;
  const float* wl = w + (size_t)(layer + 1) * 1048576;
  int co = blockIdx.x, ci = threadIdx.x;
  for (int pq = 0; pq < 4; ++pq) {
    int p = pq >> 1, q = pq & 1;
    for (int tt = 0; tt < 4; ++tt) {
      int dyi = tt >> 1, dxi = tt & 1;
      int wr = dyi ? (1 - p) : (3 - p);
      int wc = dxi ? (1 - q) : (3 - q);
      wpk[((size_t)layer * 1048576) + ((size_t)((pq * 4 + tt) * 256 + co) * 256) + ci] =
          (short)f2bf(wl[((size_t)(ci * 256 + co)) * 16 + wr * 4 + wc]);
    }
  }
}

// pack stage-5 conv weights: wB[co][c*288 + e*32 + cl] = w[co][(c*32+cl)*9 + e], bf16
__global__ void k_packc5(const float* __restrict__ w, short* __restrict__ wB) {
  int co = blockIdx.x;
  for (int kk = threadIdx.x; kk < 2304; kk += 256) {
    int c = kk / 288, r = kk % 288;
    int e = r >> 5, cl = r & 31;
    wB[(size_t)co * 2304 + kk] = (short)f2bf(w[(size_t)co * 2304 + (size_t)(c * 32 + cl) * 9 + e]);
  }
}

// pack in_w / out_w to bf16 (already k-contiguous row-major)
__global__ void k_packrow(const float* __restrict__ w, short* __restrict__ wB) {
  int o = blockIdx.x, k = threadIdx.x;
  wB[(size_t)o * 256 + k] = (short)f2bf(w[(size_t)o * 256 + k]);
}

// MFMA conv3x3 pad1 + bias, O output rows per block. Weights direct-from-global.
template <int S, int O>
__global__ __launch_bounds__(256) void k_conv3u(const unsigned* __restrict__ xp,
                                                const short* __restrict__ wpk,
                                                const float* __restrict__ bias,
                                                unsigned* __restrict__ yp) {
  constexpr int WPC = (S >= 64) ? 2 : 1;
  constexpr int WCO = 4 / WPC;
  constexpr int COS = 64 / WCO;
  constexpr int MR = COS / 16;
  constexpr int PSP = S / WPC;
  constexpr int NR = PSP / 16;
  constexpr int CBK = (S + 2 + 31) / 32;
  constexpr int RS = O + 2;
  __shared__ short x_s[RS * (S + 2) * PCI];
  unsigned* x_s32 = (unsigned*)x_s;
  int t = threadIdx.x, l = t & 63, wv = t >> 6;
  int wcob = (wv % WCO) * COS;
  int wposb = (wv / WCO) * PSP;
  int row0 = blockIdx.x * O;
  int co0 = blockIdx.y * 64;
  int colb = t & 31, ci2b = t >> 5;
  f32x4 acc[O][MR][NR];
#pragma unroll
  for (int o = 0; o < O; ++o)
#pragma unroll
    for (int m = 0; m < MR; ++m)
#pragma unroll
      for (int n = 0; n < NR; ++n) { f32x4 z = {0.f, 0.f, 0.f, 0.f}; acc[o][m][n] = z; }
  for (int c0 = 0; c0 < CCH; c0 += 32) {
    int cb = c0 >> 1;
    __syncthreads();
#pragma unroll
    for (int r = 0; r < RS; ++r) {
      int gy = row0 - 1 + r;
      bool yok = (gy >= 0 && gy < S);
#pragma unroll
      for (int cbk = 0; cbk < CBK; ++cbk) {
        int col = colb + cbk * 32;
        if (col < S + 2) {
          int gx = col - 1;
          bool ok = yok && (gx >= 0) && (gx < S);
          unsigned v0 = 0, v1 = 0;
          if (ok) {
            size_t gbase = (size_t)(cb + ci2b) * S * S + (size_t)gy * S + gx;
            v0 = xp[gbase];
            v1 = xp[gbase + (size_t)8 * S * S];
          }
          int lb = (r * (S + 2) + col) * (PCI / 2);
          x_s32[lb + ci2b] = v0;
          x_s32[lb + ci2b + 8] = v1;
        }
      }
    }
    __syncthreads();
#pragma unroll
    for (int dyg = 0; dyg < 3; ++dyg)
#pragma unroll
      for (int dx = 0; dx < 3; ++dx) {
        short8 a[MR];
#pragma unroll
        for (int m = 0; m < MR; ++m)
          a[m] = *(const short8*)&wpk[((size_t)((dyg * 3 + dx) * 256 + co0 + wcob + m * 16 + (l & 15)) * 256) + c0 + (l >> 4) * 8];
#pragma unroll
        for (int o = 0; o < O; ++o) {
          short8 b[NR];
#pragma unroll
          for (int n = 0; n < NR; ++n)
            b[n] = *(const short8*)&x_s[((dyg + o) * (S + 2) + wposb + n * 16 + (l & 15) + dx) * PCI + (l >> 4) * 8];
#pragma unroll
          for (int m = 0; m < MR; ++m)
#pragma unroll
            for (int n = 0; n < NR; ++n) mfma_bf16(acc[o][m][n], a[m], b[n]);
        }
      }
  }
  asm volatile("s_nop 7\n\ts_nop 7" ::);
#pragma unroll
  for (int o = 0; o < O; ++o)
#pragma unroll
    for (int m = 0; m < MR; ++m)
#pragma unroll
      for (int n = 0; n < NR; ++n) {
        int cob = co0 + wcob + m * 16 + (l >> 4) * 4;
        int px = wposb + n * 16 + (l & 15);
#pragma unroll
        for (int r4p = 0; r4p < 2; ++r4p) {
          unsigned pk = (unsigned)f2bf(acc[o][m][n][2 * r4p] + bias[cob + 2 * r4p])
                      | ((unsigned)f2bf(acc[o][m][n][2 * r4p + 1] + bias[cob + 2 * r4p + 1]) << 16);
          yp[(size_t)((cob >> 1) + r4p) * S * S + (size_t)(row0 + o) * S + px] = pk;
        }
      }
}

// MFMA deconv4x4 s2 p2 + bias + relu, O input rows + both q parities per block.
// LDS-staged weights (8 classes), r9 structure.
template <int S, int O>
__global__ __launch_bounds__(256) void k_deconvu(const unsigned* __restrict__ xp,
                                                 const short* __restrict__ wpk,
                                                 const float* __restrict__ bias,
                                                 unsigned* __restrict__ yp) {
  constexpr int WPC = (S >= 64) ? 2 : 1;
  constexpr int WCO = 4 / WPC;
  constexpr int COS = 64 / WCO;
  constexpr int MR = COS / 16;
  constexpr int PSP = S / WPC;
  constexpr int NR = PSP / 16;
  constexpr int CBK = (S + 2 + 31) / 32;
  constexpr int RS = O + 1;
  const int SO = 2 * S;
  __shared__ short x_s[RS * (S + 2) * PCI];
  __shared__ short w_s[8 * 64 * PCI];
  unsigned* x_s32 = (unsigned*)x_s;
  int t = threadIdx.x, l = t & 63, wv = t >> 6;
  int wcob = (wv % WCO) * COS;
  int wposb = (wv / WCO) * PSP;
  int row0 = blockIdx.x * O;
  int co0 = blockIdx.y * 64;
  int p = blockIdx.z;
  int colb = t & 31, ci2b = t >> 5;
  f32x4 acc[2][O][MR][NR];
#pragma unroll
  for (int q = 0; q < 2; ++q)
#pragma unroll
    for (int o = 0; o < O; ++o)
#pragma unroll
      for (int m = 0; m < MR; ++m)
#pragma unroll
        for (int n = 0; n < NR; ++n) { f32x4 z = {0.f, 0.f, 0.f, 0.f}; acc[q][o][m][n] = z; }
  for (int c0 = 0; c0 < CCH; c0 += 32) {
    int cb = c0 >> 1;
    __syncthreads();
#pragma unroll
    for (int r = 0; r < RS; ++r) {
      int gy = row0 + p - 1 + r;
      bool yok = (gy >= 0 && gy < S);
#pragma unroll
      for (int cbk = 0; cbk < CBK; ++cbk) {
        int col = colb + cbk * 32;
        if (col < S + 2) {
          int gx = col - 1;
          bool ok = yok && (gx >= 0) && (gx < S);
          unsigned v0 = 0, v1 = 0;
          if (ok) {
            size_t gbase = (size_t)(cb + ci2b) * S * S + (size_t)gy * S + gx;
            v0 = xp[gbase];
            v1 = xp[gbase + (size_t)8 * S * S];
          }
          int lb = (r * (S + 2) + col) * (PCI / 2);
          x_s32[lb + ci2b] = v0;
          x_s32[lb + ci2b + 8] = v1;
        }
      }
    }
    for (int i = t; i < 4096; i += 256) {
      int seg8 = i & 7;
      int rowi = i >> 3;
      int c8 = rowi >> 6, co = rowi & 63;
      int qq = c8 >> 2, tt = c8 & 3;
      us4 wv4 = *(const us4*)&wpk[((size_t)(((2 * p + qq) * 4 + tt) * 256 + co0 + co) * 256) + c0 + seg8 * 4];
      *(us4*)&w_s[rowi * PCI + seg8 * 4] = wv4;
    }
    __syncthreads();
#pragma unroll
    for (int dyi = 0; dyi < 2; ++dyi)
#pragma unroll
      for (int o = 0; o < O; ++o) {
        short8 b[3][NR];
#pragma unroll
        for (int off = 0; off < 3; ++off)
#pragma unroll
          for (int n = 0; n < NR; ++n)
            b[off][n] = *(const short8*)&x_s[((dyi + o) * (S + 2) + wposb + n * 16 + (l & 15) + off) * PCI + (l >> 4) * 8];
#pragma unroll
        for (int q = 0; q < 2; ++q)
#pragma unroll
          for (int dxi = 0; dxi < 2; ++dxi) {
            int c8 = q * 4 + dyi * 2 + dxi;
            short8 a[MR];
#pragma unroll
            for (int m = 0; m < MR; ++m)
              a[m] = *(const short8*)&w_s[(c8 * 64 + wcob + m * 16 + (l & 15)) * PCI + (l >> 4) * 8];
#pragma unroll
            for (int m = 0; m < MR; ++m)
#pragma unroll
              for (int n = 0; n < NR; ++n) mfma_bf16(acc[q][o][m][n], a[m], b[dxi + q][n]);
          }
      }
  }
  asm volatile("s_nop 7\n\ts_nop 7" ::);
#pragma unroll
  for (int o = 0; o < O; ++o) {
    int oy = 2 * (row0 + o) + p;
#pragma unroll
    for (int m = 0; m < MR; ++m)
#pragma unroll
      for (int n = 0; n < NR; ++n) {
        int px = wposb + n * 16 + (l & 15);
#pragma unroll
        for (int r4p = 0; r4p < 2; ++r4p) {
          int cob = co0 + wcob + m * 16 + (l >> 4) * 4 + 2 * r4p;
          float b0 = bias[cob], b1 = bias[cob + 1];
          unsigned pk0 = (unsigned)f2bf(fmaxf(acc[0][o][m][n][2 * r4p] + b0, 0.f))
                       | ((unsigned)f2bf(fmaxf(acc[0][o][m][n][2 * r4p + 1] + b1, 0.f)) << 16);
          unsigned pk1 = (unsigned)f2bf(fmaxf(acc[1][o][m][n][2 * r4p] + b0, 0.f))
                       | ((unsigned)f2bf(fmaxf(acc[1][o][m][n][2 * r4p + 1] + b1, 0.f)) << 16);
          uint2 pk = make_uint2(pk0, pk1);
          *(uint2*)&yp[(size_t)(cob >> 1) * SO * SO + (size_t)oy * SO + 2 * px] = pk;
        }
      }
  }
}

// sparse final conv3 via MFMA -> bf16 srows
__global__ __launch_bounds__(256) void k_conv3sM(const unsigned* __restrict__ xp,
                                                 const short* __restrict__ wB,
                                                 const float* __restrict__ bias,
                                                 const int* __restrict__ idx,
                                                 short* __restrict__ outb) {
  __shared__ short a_s[16][296];
  __shared__ int py_s[16], px_s[16];
  int t = threadIdx.x, l = t & 63, wv = t >> 6;
  int j0 = blockIdx.x * 16;
  int co0 = blockIdx.y * 128 + wv * 32;
  if (t < 16) {
    int p = idx[j0 + t];
    py_s[t] = p >> 8;
    px_s[t] = p & 255;
  }
  f32x4 acc[2];
  { f32x4 z = {0.f, 0.f, 0.f, 0.f}; acc[0] = z; acc[1] = z; }
  for (int c = 0; c < 8; ++c) {
    __syncthreads();
    for (int i = t; i < 2304; i += 256) {
      int ci2 = i & 15;
      int je = i >> 4;
      int j = je / 9, e = je % 9;
      int gy = py_s[j] - 1 + e / 3, gx = px_s[j] - 1 + e % 3;
      unsigned v = 0;
      if (gy >= 0 && gy < 256 && gx >= 0 && gx < 256)
        v = xp[(size_t)(c * 16 + ci2) * HWP + gy * 256 + gx];
      *(unsigned*)&a_s[j][e * 32 + 2 * ci2] = v;
    }
    __syncthreads();
#pragma unroll
    for (int s = 0; s < 9; ++s) {
      short8 a = *(const short8*)&a_s[l & 15][s * 32 + (l >> 4) * 8];
      int kg = c * 288 + s * 32 + (l >> 4) * 8;
      short8 b0 = *(const short8*)&wB[(size_t)(co0 + (l & 15)) * 2304 + kg];
      short8 b1 = *(const short8*)&wB[(size_t)(co0 + 16 + (l & 15)) * 2304 + kg];
      mfma_bf16(acc[0], a, b0);
      mfma_bf16(acc[1], a, b1);
    }
  }
  asm volatile("s_nop 7\n\ts_nop 7" ::);
#pragma unroll
  for (int n = 0; n < 2; ++n)
#pragma unroll
    for (int r = 0; r < 4; ++r) {
      int j = j0 + (l >> 4) * 4 + r;
      int co = co0 + n * 16 + (l & 15);
      outb[(size_t)j * 256 + co] = (short)f2bf(acc[n][r] + bias[co]);
    }
}

// gate partials + passthrough copy: block = (p-tile 256, c-chunk of 32)
__global__ void k_gatecopy2(const float* __restrict__ down, const float* __restrict__ gw,
                            float* __restrict__ out, float* __restrict__ gpart) {
  int p = blockIdx.x * 256 + threadIdx.x;
  int cc = blockIdx.y;
  float acc = 0.f;
  for (int c = cc * 32; c < cc * 32 + 32; ++c) {
    float v = down[(size_t)c * HWP + p];
    out[(size_t)c * HWP + p] = v;
    acc += v * gw[c];
  }
  gpart[(size_t)cc * HWP + p] = acc;
}

// deterministic reduce of gate partials -> orderable keys
__global__ void k_gkey(const float* __restrict__ gpart, unsigned* __restrict__ keys) {
  int p = blockIdx.x * 256 + threadIdx.x;
  float s = 0.f;
  for (int cc = 0; cc < 8; ++cc) s += gpart[(size_t)cc * HWP + p];
  unsigned u = __float_as_uint(s);
  keys[p] = (u & 0x80000000u) ? ~u : (u | 0x80000000u);
}

__global__ void k_hist(const unsigned int* __restrict__ keys, unsigned int* hist,
                       const SelState* st, int r) {
  __shared__ unsigned int lh[256];
  int t = threadIdx.x;
  lh[t] = 0;
  __syncthreads();
  unsigned int key = keys[blockIdx.x * 256 + t];
  bool ok = (r == 0) || ((key >> (32 - 8 * r)) == st->P);
  if (ok) atomicAdd(&lh[(key >> (24 - 8 * r)) & 255u], 1u);
  __syncthreads();
  if (lh[t]) atomicAdd(&hist[t], lh[t]);
}

__global__ void k_scan(unsigned int* hist, SelState* st) {
  if (threadIdx.x == 0) {
    int need = st->kneed;
    unsigned int cum = 0;
    for (int b = 255; b >= 0; --b) {
      unsigned int h = hist[b];
      if (cum + h >= (unsigned int)need) {
        st->P = (st->P << 8) | (unsigned int)b;
        st->kneed = need - (int)cum;
        break;
      }
      cum += h;
    }
  }
  __syncthreads();
  hist[threadIdx.x] = 0;
}

__global__ void k_compact(const unsigned int* __restrict__ keys, SelState* st,
                          int* __restrict__ idx, int* __restrict__ eq) {
  int p = blockIdx.x * 256 + threadIdx.x;
  unsigned int key = keys[p];
  unsigned int P = st->P;
  if (key > P) {
    int pos = atomicAdd(&st->nGreater, 1);
    idx[pos] = p;
  } else if (key == P) {
    int e = atomicAdd(&st->nEqual, 1);
    if (e < 4096) eq[e] = p;
  }
}

__global__ void k_finalize(SelState* st, int* idx, int* eq) {
  if (threadIdx.x != 0) return;
  int n = st->nEqual;
  if (n > 4096) n = 4096;
  for (int i = 1; i < n; ++i) {
    int v = eq[i], j = i - 1;
    while (j >= 0 && eq[j] > v) { eq[j + 1] = eq[j]; --j; }
    eq[j + 1] = v;
  }
  int g = st->nGreater;
  for (int i = 0; i < st->kneed; ++i) idx[g + i] = eq[i];
}

// gather down rows at idx -> bf16 dq[2048][256]
__global__ void k_gatherq(const float* __restrict__ down, const int* __restrict__ idx,
                          short* __restrict__ dq) {
  int j = blockIdx.x, c = threadIdx.x;
  int p = idx[j];
  dq[(size_t)j * 256 + c] = (short)f2bf(down[(size_t)c * HWP + p]);
}

// MFMA in-projection: [2048 x 768, K=256]. grid (128 j-tiles, 12 out-tiles of 64).
// out-tiles 0-3 = Q (A=dq), 4-7 = K, 8-11 = V (A=srows).
__global__ __launch_bounds__(256) void k_qkv3(const short* __restrict__ dq,
                                              const short* __restrict__ sr,
                                              const short* __restrict__ wBi,
                                              const float* __restrict__ bias,
                                              short* __restrict__ Qb,
                                              short* __restrict__ Kb,
                                              short* __restrict__ Vt) {
  __shared__ short a_s[16 * 264];
  unsigned* a_s32 = (unsigned*)a_s;
  int t = threadIdx.x, l = t & 63, wv = t >> 6;
  int j0 = blockIdx.x * 16;
  int third = blockIdx.y >> 2;
  const unsigned* s32 = (const unsigned*)(third ? sr : dq);
  for (int i = t; i < 2048; i += 256) {
    int row = i >> 7, c2 = i & 127;
    a_s32[row * 132 + c2] = s32[(size_t)(j0 + row) * 128 + c2];
  }
  __syncthreads();
  int cog = blockIdx.y * 64 + wv * 16 + (l & 15);
  f32x4 acc = {0.f, 0.f, 0.f, 0.f};
  const short* brow = wBi + (size_t)cog * 256 + (l >> 4) * 8;
  const short* arow = a_s + (l & 15) * 264 + (l >> 4) * 8;
#pragma unroll
  for (int kc = 0; kc < 8; ++kc) {
    short8 a = *(const short8*)(arow + kc * 32);
    short8 b = *(const short8*)(brow + kc * 32);
    mfma_bf16(acc, a, b);
  }
  asm volatile("s_nop 7\n\ts_nop 7" ::);
  float bv = bias[cog];
  int co = cog & 255;
  int h = co >> 5, d = co & 31;
#pragma unroll
  for (int r = 0; r < 4; ++r) {
    int j = j0 + (l >> 4) * 4 + r;
    short v = (short)f2bf(acc[r] + bv);
    if (third == 0)      Qb[((size_t)h * 2048 + j) * 32 + d] = v;
    else if (third == 1) Kb[((size_t)h * 2048 + j) * 32 + d] = v;
    else                 Vt[((size_t)h * 32 + d) * 2048 + j] = v;
  }
}

// fused flash attention: QK^T -> online softmax -> PV. grid (32 qtiles, 8 h), 4 waves.
// Writes bf16 Ob[j][256].
__global__ __launch_bounds__(256) void k_fattn(const short* __restrict__ Qb,
                                               const short* __restrict__ Kb,
                                               const short* __restrict__ Vt,
                                               short* __restrict__ Ob) {
  __shared__ short P_lds[4][16][136];
  int t = threadIdx.x, l = t & 63, wv = t >> 6;
  int h = blockIdx.y;
  int q0 = blockIdx.x * 64 + wv * 16;
  const short* Qh = Qb + (size_t)h * 2048 * 32;
  const short* Kh = Kb + (size_t)h * 2048 * 32;
  const short* Vh = Vt + (size_t)h * 32 * 2048;
  short8 a_q = *(const short8*)&Qh[(size_t)(q0 + (l & 15)) * 32 + (l >> 4) * 8];
  f32x4 o0 = {0.f, 0.f, 0.f, 0.f}, o1 = {0.f, 0.f, 0.f, 0.f};
  float m_run[4], l_run[4];
#pragma unroll
  for (int r = 0; r < 4; ++r) { m_run[r] = -3e38f; l_run[r] = 0.f; }
  const float scale = 0.17677669529663687f;
  for (int k0 = 0; k0 < 2048; k0 += 128) {
    f32x4 s[8];
#pragma unroll
    for (int kt = 0; kt < 8; ++kt) {
      f32x4 z = {0.f, 0.f, 0.f, 0.f};
      s[kt] = z;
      short8 b = *(const short8*)&Kh[(size_t)(k0 + kt * 16 + (l & 15)) * 32 + (l >> 4) * 8];
      mfma_bf16(s[kt], a_q, b);
    }
    asm volatile("s_nop 7\n\ts_nop 7" ::);
    float tm[4];
#pragma unroll
    for (int r = 0; r < 4; ++r) {
      float mx = s[0][r];
#pragma unroll
      for (int kt = 1; kt < 8; ++kt) mx = fmaxf(mx, s[kt][r]);
      tm[r] = mx * scale;
    }
#pragma unroll
    for (int mask = 1; mask < 16; mask <<= 1)
#pragma unroll
      for (int r = 0; r < 4; ++r) tm[r] = fmaxf(tm[r], __shfl_xor(tm[r], mask));
    float mn[4], al[4], rs[4];
#pragma unroll
    for (int r = 0; r < 4; ++r) {
      mn[r] = fmaxf(m_run[r], tm[r]);
      al[r] = __expf(m_run[r] - mn[r]);
      rs[r] = 0.f;
    }
#pragma unroll
    for (int kt = 0; kt < 8; ++kt)
#pragma unroll
      for (int r = 0; r < 4; ++r) {
        float pv = __expf(s[kt][r] * scale - mn[r]);
        s[kt][r] = pv;
        rs[r] += pv;
      }
#pragma unroll
    for (int mask = 1; mask < 16; mask <<= 1)
#pragma unroll
      for (int r = 0; r < 4; ++r) rs[r] += __shfl_xor(rs[r], mask);
#pragma unroll
    for (int r = 0; r < 4; ++r) {
      l_run[r] = l_run[r] * al[r] + rs[r];
      m_run[r] = mn[r];
      o0[r] *= al[r];
      o1[r] *= al[r];
    }
#pragma unroll
    for (int kt = 0; kt < 8; ++kt)
#pragma unroll
      for (int r = 0; r < 4; ++r)
        P_lds[wv][(l >> 4) * 4 + r][kt * 16 + (l & 15)] = (short)f2bf(s[kt][r]);
#pragma unroll
    for (int kc = 0; kc < 4; ++kc) {
      short8 ap = *(const short8*)&P_lds[wv][l & 15][kc * 32 + (l >> 4) * 8];
      short8 b0 = *(const short8*)&Vh[(size_t)(l & 15) * 2048 + k0 + kc * 32 + (l >> 4) * 8];
      short8 b1 = *(const short8*)&Vh[(size_t)(16 + (l & 15)) * 2048 + k0 + kc * 32 + (l >> 4) * 8];
      mfma_bf16(o0, ap, b0);
      mfma_bf16(o1, ap, b1);
    }
  }
  asm volatile("s_nop 7\n\ts_nop 7" ::);
#pragma unroll
  for (int r = 0; r < 4; ++r) {
    float inv = 1.f / l_run[r];
    int qr = q0 + (l >> 4) * 4 + r;
    Ob[(size_t)qr * 256 + h * 32 + (l & 15)] = (short)f2bf(o0[r] * inv);
    Ob[(size_t)qr * 256 + h * 32 + 16 + (l & 15)] = (short)f2bf(o1[r] * inv);
  }
}

// MFMA out-projection + scatter. grid (128 j-tiles, 4 co-tiles of 64).
__global__ __launch_bounds__(256) void k_outprojM(const short* __restrict__ Ob,
                                                  const short* __restrict__ wBo,
                                                  const float* __restrict__ ob,
                                                  const int* __restrict__ idx,
                                                  float* __restrict__ out) {
  __shared__ short a_s[16 * 264];
  __shared__ int jp[16];
  unsigned* a_s32 = (unsigned*)a_s;
  const unsigned* s32 = (const unsigned*)Ob;
  int t = threadIdx.x, l = t & 63, wv = t >> 6;
  int j0 = blockIdx.x * 16;
  if (t < 16) jp[t] = idx[j0 + t];
  for (int i = t; i < 2048; i += 256) {
    int row = i >> 7, c2 = i & 127;
    a_s32[row * 132 + c2] = s32[(size_t)(j0 + row) * 128 + c2];
  }
  __syncthreads();
  int co = blockIdx.y * 64 + wv * 16 + (l & 15);
  f32x4 acc = {0.f, 0.f, 0.f, 0.f};
  const short* brow = wBo + (size_t)co * 256 + (l >> 4) * 8;
  const short* arow = a_s + (l & 15) * 264 + (l >> 4) * 8;
#pragma unroll
  for (int kc = 0; kc < 8; ++kc) {
    short8 a = *(const short8*)(arow + kc * 32);
    short8 b = *(const short8*)(brow + kc * 32);
    mfma_bf16(acc, a, b);
  }
  asm volatile("s_nop 7\n\ts_nop 7" ::);
  float bv = ob[co];
#pragma unroll
  for (int r = 0; r < 4; ++r) {
    int jl = (l >> 4) * 4 + r;
    out[(size_t)co * HWP + jp[jl]] = acc[r] + bv;
  }
}

extern "C" void kernel_launch(void* const* d_in, const int* in_sizes, int n_in,
                              void* d_out, int out_size, void* d_ws, size_t ws_size,
                              hipStream_t stream) {
  const float* down  = (const float*)d_in[0];
  const float* swint = (const float*)d_in[1];
  const float* wt_w  = (const float*)d_in[2];
  const float* wt_b  = (const float*)d_in[3];
  const float* up_dw = (const float*)d_in[4];
  const float* up_db = (const float*)d_in[5];
  const float* up_cw = (const float*)d_in[6];
  const float* up_cb = (const float*)d_in[7];
  const float* gate_w = (const float*)d_in[8];
  const float* in_w  = (const float*)d_in[10];
  const float* in_b  = (const float*)d_in[11];
  const float* out_w = (const float*)d_in[12];
  const float* out_b = (const float*)d_in[13];
  float* out = (float*)d_out;
  char* ws = (char*)d_ws;

  float* bufA = (float*)ws;
  unsigned* actA = (unsigned*)ws;
  unsigned* actB = (unsigned*)(ws + BUF_B_OFF);
  unsigned int* keys = (unsigned int*)(ws + KEYS_OFF);
  unsigned int* hist = (unsigned int*)(ws + HIST_OFF);
  SelState* st = (SelState*)(ws + STATE_OFF);
  int* idx = (int*)(ws + IDX_OFF);
  int* eq = (int*)(ws + EQ_OFF);
  short* Ob = (short*)(ws + OB_OFF);
  short* wBi = (short*)(ws + WBI_OFF);
  short* wBo = (short*)(ws + WBO_OFF);
  short* srowsb = (short*)(ws + SROWS_OFF);
  short* dq = (short*)(ws + DQ_OFF);
  float* gpart = (float*)(ws + GPART_OFF);
  short* wB5 = (short*)(ws + WT5_OFF);
  short* Qb = (short*)(ws + QB_OFF);
  short* Kb = (short*)(ws + KB_OFF);
  short* Vt = (short*)(ws + VT_OFF);
  short* cpk = (short*)(ws + CPK_OFF);
  short* dpk = (short*)(ws + DPK_OFF);

  k_init<<<1, 256, 0, stream>>>(hist, st);

  // gate partials + passthrough copy (2048 blocks), deterministic key reduce,
  // then exact top-k (radix select)
  k_gatecopy2<<<dim3(256, 8), 256, 0, stream>>>(down, gate_w, out, gpart);
  k_gkey<<<256, 256, 0, stream>>>(gpart, keys);
  for (int r = 0; r < 4; ++r) {
    k_hist<<<256, 256, 0, stream>>>(keys, hist, st, r);
    k_scan<<<1, 256, 0, stream>>>(hist, st);
  }
  k_compact<<<256, 256, 0, stream>>>(keys, st, idx, eq);
  k_finalize<<<1, 64, 0, stream>>>(st, idx, eq);

  // gather selected down rows to bf16
  k_gatherq<<<2048, 256, 0, stream>>>(down, idx, dq);

  // weight packs
  k_packc3<<<dim3(256, 4), 256, 0, stream>>>(up_cw, cpk);
  k_packdc<<<dim3(256, 4), 256, 0, stream>>>(up_dw, dpk);
  k_packc5<<<256, 256, 0, stream>>>(up_cw + 2359296, wB5);
  k_packrow<<<768, 256, 0, stream>>>(in_w, wBi);
  k_packrow<<<256, 256, 0, stream>>>(out_w, wBo);

  // upsampler chain: MFMA bf16 implicit-GEMM, packed-bf16 activations (A/B ping-pong)
  k_wtconv<<<256, 64, 0, stream>>>(swint, wt_w, wt_b, bufA);
  k_deconv<8><<<dim3(1, 256), 256, 0, stream>>>(bufA, up_dw, up_db, (unsigned short*)actB);
  k_conv3u<16, 2><<<dim3(8, 4), 256, 0, stream>>>(actB, cpk, up_cb, actA);
  k_deconvu<16, 2><<<dim3(8, 4, 2), 256, 0, stream>>>(actA, dpk, up_db + 256, actB);
  k_conv3u<32, 2><<<dim3(16, 4), 256, 0, stream>>>(actB, cpk + 589824, up_cb + 256, actA);
  k_deconvu<32, 2><<<dim3(16, 4, 2), 256, 0, stream>>>(actA, dpk + 1048576, up_db + 512, actB);
  k_conv3u<64, 1><<<dim3(64, 4), 256, 0, stream>>>(actB, cpk + 2 * 589824, up_cb + 512, actA);
  k_deconvu<64, 1><<<dim3(64, 4, 2), 256, 0, stream>>>(actA, dpk + 2 * 1048576, up_db + 768, actB);
  k_conv3u<128, 1><<<dim3(128, 4), 256, 0, stream>>>(actB, cpk + 3 * 589824, up_cb + 768, actA);
  k_deconvu<128, 2><<<dim3(64, 4, 2), 256, 0, stream>>>(actA, dpk + 3 * 1048576, up_db + 1024, actB);

  // final conv3 via MFMA at the 2048 gathered positions -> bf16 srows
  k_conv3sM<<<dim3(128, 2), 256, 0, stream>>>(actB, wB5, up_cb + 1024, idx, srowsb);

  // attention path: MFMA in-projection, fused flash attention, MFMA out-projection
  k_qkv3<<<dim3(128, 12), 256, 0, stream>>>(dq, srowsb, wBi, in_b, Qb, Kb, Vt);
  k_fattn<<<dim3(32, 8), 256, 0, stream>>>(Qb, Kb, Vt, Ob);
  k_outprojM<<<dim3(128, 4), 256, 0, stream>>>(Ob, wBo, out_b, idx, out);
}